// Round 12
// baseline (86.890 us; speedup 1.0000x reference)
//
#include <hip/hip_runtime.h>
#include <math.h>

#define EPS_F 1e-8f
#define NS 10
#define HDIM 256
#define ROWS_PER_BLOCK 4

// Pade [5/4] tanh: tanh x ~= x(1 + y/9 + y^2/945)/(1 + 4y/9 + y^2/63), y=x^2
#define PA1 1.1111111e-1f
#define PA2 1.0582011e-3f
#define PB1 4.4444445e-1f
#define PB2 1.5873016e-2f

// e^y on y in (-1, 0]: degree-5 monomial (Taylor@-0.5 re-expanded), rel err <= 2.4e-5
#define EB1 0.99982788f
#define EB2 0.499124189f
#define EB3 0.164268725f
#define EB4 0.0379081662f
#define EB5 0.00505442216f

typedef float f32x2 __attribute__((ext_vector_type(2)));

// ---- packed f32 math (VOP3P) — compiler never auto-emits these ----
static __device__ __forceinline__ f32x2 pkmul(f32x2 a, f32x2 b) {
    f32x2 d;
    asm("v_pk_mul_f32 %0, %1, %2" : "=v"(d) : "v"(a), "v"(b));
    return d;
}
static __device__ __forceinline__ f32x2 pkfma(f32x2 a, f32x2 b, f32x2 c) {
    f32x2 d;
    asm("v_pk_fma_f32 %0, %1, %2, %3" : "=v"(d) : "v"(a), "v"(b), "v"(c));
    return d;
}

// ---- cross-lane helpers (R10/R11-proven) ----
#define QP_XOR1 0xB1   // quad_perm [1,0,3,2]
#define QP_XOR2 0x4E   // quad_perm [2,3,0,1]
template <int CTRL>
__device__ __forceinline__ float qperm_add(float x) {
    int t = __builtin_amdgcn_update_dpp(0, __float_as_int(x), CTRL, 0xf, 0xf, true);
    return x + __int_as_float(t);
}
template <int CTRL>
__device__ __forceinline__ float xmergeq(float a, float b, int off, int lane) {
    float ra = qperm_add<CTRL>(a);
    float rb = qperm_add<CTRL>(b);
    return (lane & off) ? rb : ra;
}
__device__ __forceinline__ float xred(float a, int off) {
    return a + __shfl_xor(a, off, 64);
}
__device__ __forceinline__ float xmerge(float a, float b, int off, int lane) {
    float ra = a + __shfl_xor(a, off, 64);
    float rb = b + __shfl_xor(b, off, 64);
    return (lane & off) ? rb : ra;
}

__device__ __forceinline__ float softplus_f(float x) {
    float e = __expf(-fabsf(x));
    return fmaxf(x, 0.0f) + __logf(1.0f + e);
}

__global__ __launch_bounds__(256, 4) void intensity_loss_kernel(
    const float* __restrict__ duration,   // [B]
    const float* __restrict__ cx,         // [B,H]
    const float* __restrict__ cbarx,      // [B,H]
    const float* __restrict__ deltx,      // [B,H]
    const float* __restrict__ ox,         // [B,H]
    const float* __restrict__ W,          // [H]
    const float* __restrict__ bptr,       // [1]
    const float* __restrict__ u,          // [NS,B]
    float* __restrict__ out,              // [B]
    int B)
{
    const int wave = threadIdx.x >> 6;
    const int lane = threadIdx.x & 63;
    const int row  = blockIdx.x * ROWS_PER_BLOCK + wave;
    if (row >= B) return;

    const size_t base = (size_t)row * HDIM + (size_t)(lane << 2);

    const float4 vcx = *reinterpret_cast<const float4*>(cx    + base);
    const float4 vcb = *reinterpret_cast<const float4*>(cbarx + base);
    const float4 vdl = *reinterpret_cast<const float4*>(deltx + base);
    const float4 vox = *reinterpret_cast<const float4*>(ox    + base);
    const float4 vw  = *reinterpret_cast<const float4*>(W + (lane << 2));

    const float dur = duration[row];

    float us[NS];
#pragma unroll
    for (int s = 0; s < NS; ++s)
        us[s] = u[(size_t)s * (size_t)B + (size_t)row];

    // scalar per-row invariants; dle = -delta*dur so exponent y = dle*u in (-1,0]
    float cb[4]  = {vcb.x, vcb.y, vcb.z, vcb.w};
    float dx[4]  = {vcx.x - vcb.x, vcx.y - vcb.y, vcx.z - vcb.z, vcx.w - vcb.w};
    float dle[4] = {-vdl.x * dur, -vdl.y * dur, -vdl.z * dur, -vdl.w * dur};
    float ow[4]  = {vox.x * vw.x, vox.y * vw.y, vox.z * vw.z, vox.w * vw.w};

    // broadcast pairs (the pack dimension is k: both halves share row-invariants)
    f32x2 cbB[4], dxB[4], dleB[4], owB[4];
#pragma unroll
    for (int j = 0; j < 4; ++j) {
        cbB[j]  = (f32x2){cb[j],  cb[j]};
        dxB[j]  = (f32x2){dx[j],  dx[j]};
        dleB[j] = (f32x2){dle[j], dle[j]};
        owB[j]  = (f32x2){ow[j],  ow[j]};
    }
    const f32x2 b1B = (f32x2){EB1, EB1}, b2B = (f32x2){EB2, EB2},
                b3B = (f32x2){EB3, EB3}, b4B = (f32x2){EB4, EB4},
                b5B = (f32x2){EB5, EB5};
    const f32x2 pa1B = (f32x2){PA1, PA1}, pa2B = (f32x2){PA2, PA2},
                pb1B = (f32x2){PB1, PB1}, pb2B = (f32x2){PB2, PB2},
                oneB = (f32x2){1.0f, 1.0f};

    // evaluate a k-pair fully packed; outputs acc for (ka, kb)
    auto eval_pair = [&](f32x2 uu, float& aA, float& aB) {
        f32x2 dq[4], nq[4];
#pragma unroll
        for (int j = 0; j < 4; ++j) {
            f32x2 y  = pkmul(dleB[j], uu);               // y in (-1,0]
            f32x2 p  = pkfma(b5B, y, b4B);               // e^y Horner deg-5
            p = pkfma(p, y, b3B);
            p = pkfma(p, y, b2B);
            p = pkfma(p, y, b1B);
            p = pkfma(p, y, oneB);                        // decay
            f32x2 c  = pkfma(dxB[j], p, cbB[j]);          // c_t
            f32x2 y2 = pkmul(c, c);
            dq[j] = pkfma(y2, pkfma(y2, pb2B, pb1B), oneB);
            nq[j] = pkmul(pkmul(c, owB[j]),
                          pkfma(y2, pkfma(y2, pa2B, pa1B), oneB));
        }
        f32x2 p01 = pkmul(dq[0], dq[1]);
        f32x2 p23 = pkmul(dq[2], dq[3]);
        f32x2 N01 = pkfma(nq[1], dq[0], pkmul(nq[0], dq[1]));
        f32x2 N23 = pkfma(nq[3], dq[2], pkmul(nq[2], dq[3]));
        f32x2 Nv  = pkfma(N23, p01, pkmul(N01, p23));
        f32x2 Pv  = pkmul(p01, p23);
        float R = __builtin_amdgcn_rcpf(Pv.x * Pv.y);     // one rcp per 2 k's
        aA = Nv.x * (R * Pv.y);
        aB = Nv.y * (R * Pv.x);
    };

    // pairs aligned with the merge tree's xor1 level: (0,1),(2,3),(4,5),(6,7),(8,9)
    float a0, a1;
    eval_pair((f32x2){1.0f, us[0]}, a0, a1);              // k0 = observed (u==1)
    float m01 = xmergeq<QP_XOR1>(a0, a1, 1, lane);
    eval_pair((f32x2){us[1], us[2]}, a0, a1);
    float m23 = xmergeq<QP_XOR1>(a0, a1, 1, lane);
    eval_pair((f32x2){us[3], us[4]}, a0, a1);
    float m45 = xmergeq<QP_XOR1>(a0, a1, 1, lane);
    eval_pair((f32x2){us[5], us[6]}, a0, a1);
    float m67 = xmergeq<QP_XOR1>(a0, a1, 1, lane);
    eval_pair((f32x2){us[7], us[8]}, a0, a1);
    float m89 = xmergeq<QP_XOR1>(a0, a1, 1, lane);

    // k10: scalar eval (odd one out)
    float accT;
    {
        float dsc[4], nsc[4];
        const float u10 = us[9];
#pragma unroll
        for (int j = 0; j < 4; ++j) {
            float y = dle[j] * u10;
            float p = fmaf(EB5, y, EB4);
            p = fmaf(p, y, EB3);
            p = fmaf(p, y, EB2);
            p = fmaf(p, y, EB1);
            p = fmaf(p, y, 1.0f);
            float c  = fmaf(dx[j], p, cb[j]);
            float y2 = c * c;
            dsc[j] = fmaf(y2, fmaf(y2, PB2, PB1), 1.0f);
            nsc[j] = (c * ow[j]) * fmaf(y2, fmaf(y2, PA2, PA1), 1.0f);
        }
        float p01 = dsc[0] * dsc[1], p23 = dsc[2] * dsc[3];
        float N01 = fmaf(nsc[1], dsc[0], nsc[0] * dsc[1]);
        float N23 = fmaf(nsc[3], dsc[2], nsc[2] * dsc[3]);
        float Nv  = fmaf(N23, p01, N01 * p23);
        accT = Nv * __builtin_amdgcn_rcpf(p01 * p23);
    }
    float mA = qperm_add<QP_XOR1>(accT);

    // merge tree (R10-proven): final lane l holds wave-sum of acc[l]
    float q0 = xmergeq<QP_XOR2>(m01, m23, 2, lane);
    float q1 = xmergeq<QP_XOR2>(m45, m67, 2, lane);
    float q2 = xmergeq<QP_XOR2>(m89, mA, 2, lane);
    float p0 = xmerge(q0, q1, 4, lane);
    float p1 = xred(q2, 4);
    float f  = xmerge(p0, p1, 8, lane);
    f = xred(f, 16);
    f = xred(f, 32);

    const float bb = bptr[0];
    float sp   = softplus_f(f + bb);
    float nllv = -__logf(sp + EPS_F);
    const float scale = dur * (1.0f / (float)NS);

    float contrib = (lane == 0) ? nllv
                  : ((lane <= NS) ? sp * scale : 0.0f);

    contrib = xred(contrib, 8);
    contrib = xred(contrib, 4);
    contrib = qperm_add<QP_XOR2>(contrib);
    contrib = qperm_add<QP_XOR1>(contrib);

    if (lane == 0) out[row] = contrib;
}

extern "C" void kernel_launch(void* const* d_in, const int* in_sizes, int n_in,
                              void* d_out, int out_size, void* d_ws, size_t ws_size,
                              hipStream_t stream) {
    const float* duration = (const float*)d_in[0];
    const float* cx       = (const float*)d_in[1];
    const float* cbarx    = (const float*)d_in[2];
    const float* deltx    = (const float*)d_in[3];
    const float* ox       = (const float*)d_in[4];
    const float* W        = (const float*)d_in[5];
    const float* b        = (const float*)d_in[6];
    const float* u        = (const float*)d_in[7];
    float* out            = (float*)d_out;

    const int B = in_sizes[0];           // 65536
    const int grid = (B + ROWS_PER_BLOCK - 1) / ROWS_PER_BLOCK;

    intensity_loss_kernel<<<grid, 256, 0, stream>>>(
        duration, cx, cbarx, deltx, ox, W, b, u, out, B);
}

// Round 13
// 77.307 us; speedup vs baseline: 1.1240x; 1.1240x over previous
//
#include <hip/hip_runtime.h>
#include <math.h>

#define EPS_F 1e-8f
#define NS 10
#define NK 11
#define HDIM 256
#define ROWS_PER_BLOCK 4

// Pade [5/4] tanh: tanh x ~= x(1 + y/9 + y^2/945)/(1 + 4y/9 + y^2/63), y=x^2
#define PA1 1.1111111e-1f
#define PA2 1.0582011e-3f
#define PB1 4.4444445e-1f
#define PB2 1.5873016e-2f

// e^y on y in (-1, 0]: degree-5 monomial (Taylor@-0.5 re-expanded), rel err <= 2.4e-5
#define EB1 0.99982788f
#define EB2 0.499124189f
#define EB3 0.164268725f
#define EB4 0.0379081662f
#define EB5 0.00505442216f

// ---- cross-lane helpers (R10/R11-proven) ----
#define QP_XOR1 0xB1   // quad_perm [1,0,3,2]
#define QP_XOR2 0x4E   // quad_perm [2,3,0,1]
template <int CTRL>
__device__ __forceinline__ float qperm_add(float x) {
    int t = __builtin_amdgcn_update_dpp(0, __float_as_int(x), CTRL, 0xf, 0xf, true);
    return x + __int_as_float(t);
}
template <int CTRL>
__device__ __forceinline__ float xmergeq(float a, float b, int off, int lane) {
    float ra = qperm_add<CTRL>(a);
    float rb = qperm_add<CTRL>(b);
    return (lane & off) ? rb : ra;
}
__device__ __forceinline__ float xred(float a, int off) {
    return a + __shfl_xor(a, off, 64);
}
__device__ __forceinline__ float xmerge(float a, float b, int off, int lane) {
    float ra = a + __shfl_xor(a, off, 64);
    float rb = b + __shfl_xor(b, off, 64);
    return (lane & off) ? rb : ra;
}

__device__ __forceinline__ float softplus_f(float x) {
    float e = __expf(-fabsf(x));
    return fmaxf(x, 0.0f) + __logf(1.0f + e);
}

__global__ __launch_bounds__(256) void intensity_loss_kernel(
    const float* __restrict__ duration,   // [B]
    const float* __restrict__ cx,         // [B,H]
    const float* __restrict__ cbarx,      // [B,H]
    const float* __restrict__ deltx,      // [B,H]
    const float* __restrict__ ox,         // [B,H]
    const float* __restrict__ W,          // [H]
    const float* __restrict__ bptr,       // [1]
    const float* __restrict__ u,          // [NS,B]
    float* __restrict__ out,              // [B]
    int B)
{
    const int wave = threadIdx.x >> 6;
    const int lane = threadIdx.x & 63;
    const int row  = blockIdx.x * ROWS_PER_BLOCK + wave;
    if (row >= B) return;

    const size_t base = (size_t)row * HDIM + (size_t)(lane << 2);

    const float4 vcx = *reinterpret_cast<const float4*>(cx    + base);
    const float4 vcb = *reinterpret_cast<const float4*>(cbarx + base);
    const float4 vdl = *reinterpret_cast<const float4*>(deltx + base);
    const float4 vox = *reinterpret_cast<const float4*>(ox    + base);
    const float4 vw  = *reinterpret_cast<const float4*>(W + (lane << 2));

    const float dur = duration[row];

    // u samples (vector loads — R7-proven); slot 0 = observed eval (u == 1)
    float us[NK];
    us[0] = 1.0f;
#pragma unroll
    for (int s = 0; s < NS; ++s)
        us[s + 1] = u[(size_t)s * (size_t)B + (size_t)row];

    // per-row invariants; dle = -delta*dur so exponent y = dle*u in (-1,0];
    // ow folded into the Pade numerator coefficients
    float cb[4]  = {vcb.x, vcb.y, vcb.z, vcb.w};
    float dx[4]  = {vcx.x - vcb.x, vcx.y - vcb.y, vcx.z - vcb.z, vcx.w - vcb.w};
    float dle[4] = {-vdl.x * dur, -vdl.y * dur, -vdl.z * dur, -vdl.w * dur};
    float ow[4]  = {vox.x * vw.x, vox.y * vw.y, vox.z * vw.z, vox.w * vw.w};
    float owa1[4], owa2[4];
#pragma unroll
    for (int j = 0; j < 4; ++j) { owa1[j] = ow[j] * PA1; owa2[j] = ow[j] * PA2; }

    // Evaluate one time-sample -> single fraction N/P with sum_j n_j/d_j = N/P.
    // Poly-exp: no v_exp — 1 mul + 5 fma per element (y in (-1,0], rel 2.4e-5).
    auto eval_np = [&](float uk, bool isObs, float& N, float& P) {
        float dsc[4], nsc[4];
#pragma unroll
        for (int j = 0; j < 4; ++j) {
            float y = isObs ? dle[j] : dle[j] * uk;
            float p = fmaf(EB5, y, EB4);
            p = fmaf(p, y, EB3);
            p = fmaf(p, y, EB2);
            p = fmaf(p, y, EB1);
            p = fmaf(p, y, 1.0f);                 // decay = e^y
            float c  = fmaf(dx[j], p, cb[j]);
            float y2 = c * c;
            dsc[j] = fmaf(y2, fmaf(y2, PB2, PB1), 1.0f);
            nsc[j] = c * fmaf(y2, fmaf(y2, owa2[j], owa1[j]), ow[j]);
        }
        float p01 = dsc[0] * dsc[1], p23 = dsc[2] * dsc[3];
        float N01 = fmaf(nsc[1], dsc[0], nsc[0] * dsc[1]);
        float N23 = fmaf(nsc[3], dsc[2], nsc[2] * dsc[3]);
        N = fmaf(N23, p01, N01 * p23);     // |N| <= ~2e6, safe
        P = p01 * p23;                     // <= ~1.5e6, safe
    };

    float acc[NK];
    // k = 0 (observed eval): standalone rcp
    {
        float N0, P0;
        eval_np(1.0f, true, N0, P0);
        acc[0] = N0 * __builtin_amdgcn_rcpf(P0);
    }
    // k = 1..10 in pairs sharing ONE rcp: 1/Pa = R*Pb, 1/Pb = R*Pa
#pragma unroll
    for (int i = 0; i < 5; ++i) {
        const int ka = 2 * i + 1, kb = 2 * i + 2;
        float Na, Pa, Nb, Pb;
        eval_np(us[ka], false, Na, Pa);
        eval_np(us[kb], false, Nb, Pb);
        float R = __builtin_amdgcn_rcpf(Pa * Pb);   // <= ~2.3e12, safe
        acc[ka] = Na * (R * Pb);
        acc[kb] = Nb * (R * Pa);
    }

    // merged multi-value butterfly; xor1/xor2 via quad_perm DPP (VALU),
    // xor4/8/16/32 via DS shuffles. Final: lane l holds wave-sum of acc[l].
    float m01 = xmergeq<QP_XOR1>(acc[0], acc[1], 1, lane);
    float m23 = xmergeq<QP_XOR1>(acc[2], acc[3], 1, lane);
    float m45 = xmergeq<QP_XOR1>(acc[4], acc[5], 1, lane);
    float m67 = xmergeq<QP_XOR1>(acc[6], acc[7], 1, lane);
    float m89 = xmergeq<QP_XOR1>(acc[8], acc[9], 1, lane);
    float mA  = qperm_add<QP_XOR1>(acc[10]);
    float q0 = xmergeq<QP_XOR2>(m01, m23, 2, lane);
    float q1 = xmergeq<QP_XOR2>(m45, m67, 2, lane);
    float q2 = xmergeq<QP_XOR2>(m89, mA, 2, lane);
    float p0 = xmerge(q0, q1, 4, lane);
    float p1 = xred(q2, 4);
    float f  = xmerge(p0, p1, 8, lane);
    f = xred(f, 16);
    f = xred(f, 32);

    const float bb = bptr[0];
    float sp   = softplus_f(f + bb);
    float nllv = -__logf(sp + EPS_F);
    const float scale = dur * (1.0f / (float)NS);

    float contrib = (lane == 0) ? nllv
                  : ((lane <= NS) ? sp * scale : 0.0f);

    // lanes 0..10: reduce within 16 — xor8,4 via DS; xor2,1 via DPP
    contrib = xred(contrib, 8);
    contrib = xred(contrib, 4);
    contrib = qperm_add<QP_XOR2>(contrib);
    contrib = qperm_add<QP_XOR1>(contrib);

    if (lane == 0) out[row] = contrib;
}

extern "C" void kernel_launch(void* const* d_in, const int* in_sizes, int n_in,
                              void* d_out, int out_size, void* d_ws, size_t ws_size,
                              hipStream_t stream) {
    const float* duration = (const float*)d_in[0];
    const float* cx       = (const float*)d_in[1];
    const float* cbarx    = (const float*)d_in[2];
    const float* deltx    = (const float*)d_in[3];
    const float* ox       = (const float*)d_in[4];
    const float* W        = (const float*)d_in[5];
    const float* b        = (const float*)d_in[6];
    const float* u        = (const float*)d_in[7];
    float* out            = (float*)d_out;

    const int B = in_sizes[0];           // 65536
    const int grid = (B + ROWS_PER_BLOCK - 1) / ROWS_PER_BLOCK;

    intensity_loss_kernel<<<grid, 256, 0, stream>>>(
        duration, cx, cbarx, deltx, ox, W, b, u, out, B);
}

// Round 14
// 70.884 us; speedup vs baseline: 1.2258x; 1.0906x over previous
//
#include <hip/hip_runtime.h>
#include <math.h>

#define EPS_F 1e-8f
#define NS 10
#define NK 11
#define HDIM 256
#define ROWS_PER_BLOCK 4

// Pade [5/4] tanh: tanh x ~= x(1 + y/9 + y^2/945)/(1 + 4y/9 + y^2/63), y=x^2
#define PA1 1.1111111e-1f
#define PA2 1.0582011e-3f
#define PB1 4.4444445e-1f
#define PB2 1.5873016e-2f

// Chebyshev-economized deg-4 for e^y on y in (-1,0]: rel err <= ~2e-5
// e^y ~= B0 + B1 y + B2 y^2 + B3 y^3 + B4 y^4
#define XB0 0.99999994f
#define XB1 0.99935830f
#define XB2 0.49517566f
#define XB3 0.15321280f
#define XB4 0.02527212f

// ---- cross-lane helpers (R10/R11-proven) ----
#define QP_XOR1 0xB1   // quad_perm [1,0,3,2]
#define QP_XOR2 0x4E   // quad_perm [2,3,0,1]
template <int CTRL>
__device__ __forceinline__ float qperm_add(float x) {
    int t = __builtin_amdgcn_update_dpp(0, __float_as_int(x), CTRL, 0xf, 0xf, true);
    return x + __int_as_float(t);
}
template <int CTRL>
__device__ __forceinline__ float xmergeq(float a, float b, int off, int lane) {
    float ra = qperm_add<CTRL>(a);
    float rb = qperm_add<CTRL>(b);
    return (lane & off) ? rb : ra;
}
__device__ __forceinline__ float xred(float a, int off) {
    return a + __shfl_xor(a, off, 64);
}
__device__ __forceinline__ float xmerge(float a, float b, int off, int lane) {
    float ra = a + __shfl_xor(a, off, 64);
    float rb = b + __shfl_xor(b, off, 64);
    return (lane & off) ? rb : ra;
}

__device__ __forceinline__ float softplus_f(float x) {
    float e = __expf(-fabsf(x));
    return fmaxf(x, 0.0f) + __logf(1.0f + e);
}

__global__ __launch_bounds__(256) void intensity_loss_kernel(
    const float* __restrict__ duration,   // [B]
    const float* __restrict__ cx,         // [B,H]
    const float* __restrict__ cbarx,      // [B,H]
    const float* __restrict__ deltx,      // [B,H]
    const float* __restrict__ ox,         // [B,H]
    const float* __restrict__ W,          // [H]
    const float* __restrict__ bptr,       // [1]
    const float* __restrict__ u,          // [NS,B]
    float* __restrict__ out,              // [B]
    int B)
{
    const int wave = threadIdx.x >> 6;
    const int lane = threadIdx.x & 63;
    const int row  = blockIdx.x * ROWS_PER_BLOCK + wave;
    if (row >= B) return;

    const size_t base = (size_t)row * HDIM + (size_t)(lane << 2);

    const float4 vcx = *reinterpret_cast<const float4*>(cx    + base);
    const float4 vcb = *reinterpret_cast<const float4*>(cbarx + base);
    const float4 vdl = *reinterpret_cast<const float4*>(deltx + base);
    const float4 vox = *reinterpret_cast<const float4*>(ox    + base);
    const float4 vw  = *reinterpret_cast<const float4*>(W + (lane << 2));

    const float dur = duration[row];

    // u samples (vector loads — R7-proven); slot 0 = observed eval (u == 1)
    float us[NK];
    us[0] = 1.0f;
#pragma unroll
    for (int s = 0; s < NS; ++s)
        us[s + 1] = u[(size_t)s * (size_t)B + (size_t)row];

    // per-row invariants
    float cb[4]  = {vcb.x, vcb.y, vcb.z, vcb.w};
    float dx[4]  = {vcx.x - vcb.x, vcx.y - vcb.y, vcx.z - vcb.z, vcx.w - vcb.w};
    float dle[4] = {-vdl.x * dur, -vdl.y * dur, -vdl.z * dur, -vdl.w * dur};
    float ow[4]  = {vox.x * vw.x, vox.y * vw.y, vox.z * vw.z, vox.w * vw.w};
    float owa1[4], owa2[4];
#pragma unroll
    for (int j = 0; j < 4; ++j) { owa1[j] = ow[j] * PA1; owa2[j] = ow[j] * PA2; }

    // Fold EVERYTHING up to c_t into a quartic in u with per-element coeffs:
    // c(u) = cb + dx*e^{dle*u} ~= q0 + q1 u + q2 u^2 + q3 u^3 + q4 u^4
    // (exp deg-4 Chebyshev on (-1,0], rel err ~2e-5). Eval cost: 4 fma.
    float q0[4], q1[4], q2[4], q3[4], q4[4];
#pragma unroll
    for (int j = 0; j < 4; ++j) {
        float t1 = dx[j] * dle[j];
        float t2 = t1 * dle[j];
        float t3 = t2 * dle[j];
        float t4 = t3 * dle[j];
        q0[j] = fmaf(dx[j], XB0, cb[j]);
        q1[j] = XB1 * t1;
        q2[j] = XB2 * t2;
        q3[j] = XB3 * t3;
        q4[j] = XB4 * t4;
    }

    // Evaluate one time-sample -> single fraction N/P with sum_j n_j/d_j = N/P.
    auto eval_np = [&](float uk, float& N, float& P) {
        float dsc[4], nsc[4];
#pragma unroll
        for (int j = 0; j < 4; ++j) {
            float c = fmaf(q4[j], uk, q3[j]);
            c = fmaf(c, uk, q2[j]);
            c = fmaf(c, uk, q1[j]);
            c = fmaf(c, uk, q0[j]);               // c_t (exp folded in)
            float y2 = c * c;
            dsc[j] = fmaf(y2, fmaf(y2, PB2, PB1), 1.0f);
            nsc[j] = c * fmaf(y2, fmaf(y2, owa2[j], owa1[j]), ow[j]);
        }
        float p01 = dsc[0] * dsc[1], p23 = dsc[2] * dsc[3];
        float N01 = fmaf(nsc[1], dsc[0], nsc[0] * dsc[1]);
        float N23 = fmaf(nsc[3], dsc[2], nsc[2] * dsc[3]);
        N = fmaf(N23, p01, N01 * p23);     // |N| <= ~2e6, safe
        P = p01 * p23;                     // <= ~1.5e6, safe
    };

    float acc[NK];
    // k = 0 (observed eval, u==1): standalone rcp
    {
        float N0, P0;
        eval_np(1.0f, N0, P0);
        acc[0] = N0 * __builtin_amdgcn_rcpf(P0);
    }
    // k = 1..10 in pairs sharing ONE rcp: 1/Pa = R*Pb, 1/Pb = R*Pa
#pragma unroll
    for (int i = 0; i < 5; ++i) {
        const int ka = 2 * i + 1, kb = 2 * i + 2;
        float Na, Pa, Nb, Pb;
        eval_np(us[ka], Na, Pa);
        eval_np(us[kb], Nb, Pb);
        float R = __builtin_amdgcn_rcpf(Pa * Pb);   // <= ~2.3e12, safe
        acc[ka] = Na * (R * Pb);
        acc[kb] = Nb * (R * Pa);
    }

    // merged multi-value butterfly; xor1/xor2 via quad_perm DPP (VALU),
    // xor4/8/16/32 via DS shuffles. Final: lane l holds wave-sum of acc[l].
    float m01 = xmergeq<QP_XOR1>(acc[0], acc[1], 1, lane);
    float m23 = xmergeq<QP_XOR1>(acc[2], acc[3], 1, lane);
    float m45 = xmergeq<QP_XOR1>(acc[4], acc[5], 1, lane);
    float m67 = xmergeq<QP_XOR1>(acc[6], acc[7], 1, lane);
    float m89 = xmergeq<QP_XOR1>(acc[8], acc[9], 1, lane);
    float mA  = qperm_add<QP_XOR1>(acc[10]);
    float qq0 = xmergeq<QP_XOR2>(m01, m23, 2, lane);
    float qq1 = xmergeq<QP_XOR2>(m45, m67, 2, lane);
    float qq2 = xmergeq<QP_XOR2>(m89, mA, 2, lane);
    float p0 = xmerge(qq0, qq1, 4, lane);
    float p1 = xred(qq2, 4);
    float f  = xmerge(p0, p1, 8, lane);
    f = xred(f, 16);
    f = xred(f, 32);

    const float bb = bptr[0];
    float sp   = softplus_f(f + bb);
    float nllv = -__logf(sp + EPS_F);
    const float scale = dur * (1.0f / (float)NS);

    float contrib = (lane == 0) ? nllv
                  : ((lane <= NS) ? sp * scale : 0.0f);

    // lanes 0..10: reduce within 16 — xor8,4 via DS; xor2,1 via DPP
    contrib = xred(contrib, 8);
    contrib = xred(contrib, 4);
    contrib = qperm_add<QP_XOR2>(contrib);
    contrib = qperm_add<QP_XOR1>(contrib);

    if (lane == 0) out[row] = contrib;
}

extern "C" void kernel_launch(void* const* d_in, const int* in_sizes, int n_in,
                              void* d_out, int out_size, void* d_ws, size_t ws_size,
                              hipStream_t stream) {
    const float* duration = (const float*)d_in[0];
    const float* cx       = (const float*)d_in[1];
    const float* cbarx    = (const float*)d_in[2];
    const float* deltx    = (const float*)d_in[3];
    const float* ox       = (const float*)d_in[4];
    const float* W        = (const float*)d_in[5];
    const float* b        = (const float*)d_in[6];
    const float* u        = (const float*)d_in[7];
    float* out            = (float*)d_out;

    const int B = in_sizes[0];           // 65536
    const int grid = (B + ROWS_PER_BLOCK - 1) / ROWS_PER_BLOCK;

    intensity_loss_kernel<<<grid, 256, 0, stream>>>(
        duration, cx, cbarx, deltx, ox, W, b, u, out, B);
}

// Round 15
// 63.484 us; speedup vs baseline: 1.3687x; 1.1166x over previous
//
#include <hip/hip_runtime.h>
#include <math.h>

#define EPS_F 1e-8f
#define NS 10
#define NK 11
#define HDIM 256
#define ROWS_PER_BLOCK 4

// Pade [3/4] tanh: tanh x ~= x(1 + 2y/21)/(1 + 3y/7 + y^2/105), y=x^2
// (Taylor-matched; err: 2e-6@x=1, -5.7e-4@x=2, -5.4e-3@x=3; |c|>3 is ~1e-3 rare)
#define TA1 0.095238095f   // 2/21
#define TB1 0.428571429f   // 3/7
#define TB2 0.0095238095f  // 1/105

// deg-3 Chebyshev for e^y on y in (-1,0]: abs err <= ~3.3e-4
#define XC0 0.99983796f
#define XC1 0.99354980f
#define XC2 0.46441430f
#define XC3 0.10298410f

// ---- cross-lane helpers (R10/R11-proven) ----
#define QP_XOR1 0xB1   // quad_perm [1,0,3,2]
#define QP_XOR2 0x4E   // quad_perm [2,3,0,1]
template <int CTRL>
__device__ __forceinline__ float qperm_add(float x) {
    int t = __builtin_amdgcn_update_dpp(0, __float_as_int(x), CTRL, 0xf, 0xf, true);
    return x + __int_as_float(t);
}
template <int CTRL>
__device__ __forceinline__ float xmergeq(float a, float b, int off, int lane) {
    float ra = qperm_add<CTRL>(a);
    float rb = qperm_add<CTRL>(b);
    return (lane & off) ? rb : ra;
}
__device__ __forceinline__ float xred(float a, int off) {
    return a + __shfl_xor(a, off, 64);
}
__device__ __forceinline__ float xmerge(float a, float b, int off, int lane) {
    float ra = a + __shfl_xor(a, off, 64);
    float rb = b + __shfl_xor(b, off, 64);
    return (lane & off) ? rb : ra;
}

__device__ __forceinline__ float softplus_f(float x) {
    float e = __expf(-fabsf(x));
    return fmaxf(x, 0.0f) + __logf(1.0f + e);
}

__global__ __launch_bounds__(256) void intensity_loss_kernel(
    const float* __restrict__ duration,   // [B]
    const float* __restrict__ cx,         // [B,H]
    const float* __restrict__ cbarx,      // [B,H]
    const float* __restrict__ deltx,      // [B,H]
    const float* __restrict__ ox,         // [B,H]
    const float* __restrict__ W,          // [H]
    const float* __restrict__ bptr,       // [1]
    const float* __restrict__ u,          // [NS,B]
    float* __restrict__ out,              // [B]
    int B)
{
    const int wave = threadIdx.x >> 6;
    const int lane = threadIdx.x & 63;
    const int row  = blockIdx.x * ROWS_PER_BLOCK + wave;
    if (row >= B) return;

    const size_t base = (size_t)row * HDIM + (size_t)(lane << 2);

    const float4 vcx = *reinterpret_cast<const float4*>(cx    + base);
    const float4 vcb = *reinterpret_cast<const float4*>(cbarx + base);
    const float4 vdl = *reinterpret_cast<const float4*>(deltx + base);
    const float4 vox = *reinterpret_cast<const float4*>(ox    + base);
    const float4 vw  = *reinterpret_cast<const float4*>(W + (lane << 2));

    const float dur = duration[row];

    // u samples (vector loads — R7-proven); slot 0 = observed eval (u == 1)
    float us[NK];
    us[0] = 1.0f;
#pragma unroll
    for (int s = 0; s < NS; ++s)
        us[s + 1] = u[(size_t)s * (size_t)B + (size_t)row];

    // per-row invariants
    float cb[4]  = {vcb.x, vcb.y, vcb.z, vcb.w};
    float dx[4]  = {vcx.x - vcb.x, vcx.y - vcb.y, vcx.z - vcb.z, vcx.w - vcb.w};
    float dle[4] = {-vdl.x * dur, -vdl.y * dur, -vdl.z * dur, -vdl.w * dur};
    float ow[4]  = {vox.x * vw.x, vox.y * vw.y, vox.z * vw.z, vox.w * vw.w};
    float owa[4];
#pragma unroll
    for (int j = 0; j < 4; ++j) owa[j] = ow[j] * TA1;

    // Fold everything up to c_t into a CUBIC in u with per-element coeffs:
    // c(u) = cb + dx*e^{dle*u} ~= q0 + q1 u + q2 u^2 + q3 u^3  (3 fma/eval)
    float q0[4], q1[4], q2[4], q3[4];
#pragma unroll
    for (int j = 0; j < 4; ++j) {
        float t1 = dx[j] * dle[j];
        float t2 = t1 * dle[j];
        float t3 = t2 * dle[j];
        q0[j] = fmaf(dx[j], XC0, cb[j]);
        q1[j] = XC1 * t1;
        q2[j] = XC2 * t2;
        q3[j] = XC3 * t3;
    }

    // Evaluate one time-sample -> single fraction N/P with sum_j n_j/d_j = N/P.
    auto eval_np = [&](float uk, float& N, float& P) {
        float dsc[4], nsc[4];
#pragma unroll
        for (int j = 0; j < 4; ++j) {
            float c = fmaf(q3[j], uk, q2[j]);
            c = fmaf(c, uk, q1[j]);
            c = fmaf(c, uk, q0[j]);               // c_t (exp folded in)
            float y2 = c * c;
            dsc[j] = fmaf(y2, fmaf(y2, TB2, TB1), 1.0f);   // den in [1, ~27]
            nsc[j] = c * fmaf(y2, owa[j], ow[j]);          // ow*c*(1 + 2y/21)
        }
        float p01 = dsc[0] * dsc[1], p23 = dsc[2] * dsc[3];
        float N01 = fmaf(nsc[1], dsc[0], nsc[0] * dsc[1]);
        float N23 = fmaf(nsc[3], dsc[2], nsc[2] * dsc[3]);
        N = fmaf(N23, p01, N01 * p23);     // |N| <= ~1e6, safe
        P = p01 * p23;                     // <= ~5e5, safe
    };

    float acc[NK];
    // k = 0 (observed eval, u==1): standalone rcp
    {
        float N0, P0;
        eval_np(1.0f, N0, P0);
        acc[0] = N0 * __builtin_amdgcn_rcpf(P0);
    }
    // k = 1..10 in pairs sharing ONE rcp: 1/Pa = R*Pb, 1/Pb = R*Pa
#pragma unroll
    for (int i = 0; i < 5; ++i) {
        const int ka = 2 * i + 1, kb = 2 * i + 2;
        float Na, Pa, Nb, Pb;
        eval_np(us[ka], Na, Pa);
        eval_np(us[kb], Nb, Pb);
        float R = __builtin_amdgcn_rcpf(Pa * Pb);   // <= ~2.5e11, safe
        acc[ka] = Na * (R * Pb);
        acc[kb] = Nb * (R * Pa);
    }

    // merged multi-value butterfly; xor1/xor2 via quad_perm DPP (VALU),
    // xor4/8/16/32 via DS shuffles. Final: lane l holds wave-sum of acc[l].
    float m01 = xmergeq<QP_XOR1>(acc[0], acc[1], 1, lane);
    float m23 = xmergeq<QP_XOR1>(acc[2], acc[3], 1, lane);
    float m45 = xmergeq<QP_XOR1>(acc[4], acc[5], 1, lane);
    float m67 = xmergeq<QP_XOR1>(acc[6], acc[7], 1, lane);
    float m89 = xmergeq<QP_XOR1>(acc[8], acc[9], 1, lane);
    float mA  = qperm_add<QP_XOR1>(acc[10]);
    float qq0 = xmergeq<QP_XOR2>(m01, m23, 2, lane);
    float qq1 = xmergeq<QP_XOR2>(m45, m67, 2, lane);
    float qq2 = xmergeq<QP_XOR2>(m89, mA, 2, lane);
    float p0 = xmerge(qq0, qq1, 4, lane);
    float p1 = xred(qq2, 4);
    float f  = xmerge(p0, p1, 8, lane);
    f = xred(f, 16);
    f = xred(f, 32);

    const float bb = bptr[0];
    float sp   = softplus_f(f + bb);
    float nllv = -__logf(sp + EPS_F);
    const float scale = dur * (1.0f / (float)NS);

    float contrib = (lane == 0) ? nllv
                  : ((lane <= NS) ? sp * scale : 0.0f);

    // lanes 0..10: reduce within 16 — xor8,4 via DS; xor2,1 via DPP
    contrib = xred(contrib, 8);
    contrib = xred(contrib, 4);
    contrib = qperm_add<QP_XOR2>(contrib);
    contrib = qperm_add<QP_XOR1>(contrib);

    if (lane == 0) out[row] = contrib;
}

extern "C" void kernel_launch(void* const* d_in, const int* in_sizes, int n_in,
                              void* d_out, int out_size, void* d_ws, size_t ws_size,
                              hipStream_t stream) {
    const float* duration = (const float*)d_in[0];
    const float* cx       = (const float*)d_in[1];
    const float* cbarx    = (const float*)d_in[2];
    const float* deltx    = (const float*)d_in[3];
    const float* ox       = (const float*)d_in[4];
    const float* W        = (const float*)d_in[5];
    const float* b        = (const float*)d_in[6];
    const float* u        = (const float*)d_in[7];
    float* out            = (float*)d_out;

    const int B = in_sizes[0];           // 65536
    const int grid = (B + ROWS_PER_BLOCK - 1) / ROWS_PER_BLOCK;

    intensity_loss_kernel<<<grid, 256, 0, stream>>>(
        duration, cx, cbarx, deltx, ox, W, b, u, out, B);
}

// Round 16
// 46.295 us; speedup vs baseline: 1.8769x; 1.3713x over previous
//
#include <hip/hip_runtime.h>
#include <math.h>

#define EPS_F 1e-8f
#define NS 10
#define HDIM 256
#define ROWS_PER_BLOCK 4

// Pade [3/4] tanh: tanh x ~= x(1 + 2y/21)/(1 + 3y/7 + y^2/105)  (R15-proven)
#define TA1 0.095238095f
#define TB1 0.428571429f
#define TB2 0.0095238095f
// deg-3 Chebyshev for e^y on (-1,0]: abs err <= 3.3e-4  (R15-proven)
#define XC0 0.99983796f
#define XC1 0.99354980f
#define XC2 0.46441430f
#define XC3 0.10298410f
// Chebyshev-Lobatto nodes on [0,1]: {0, TN1, 0.5, TN3, 1}
#define TN1 0.14644661f
#define TN3 0.85355339f

// ---- cross-lane helpers (R10-R15-proven) ----
#define QP_XOR1 0xB1   // quad_perm [1,0,3,2]
#define QP_XOR2 0x4E   // quad_perm [2,3,0,1]
template <int CTRL>
__device__ __forceinline__ float qperm_add(float x) {
    int t = __builtin_amdgcn_update_dpp(0, __float_as_int(x), CTRL, 0xf, 0xf, true);
    return x + __int_as_float(t);
}
template <int CTRL>
__device__ __forceinline__ float xmergeq(float a, float b, int off, int lane) {
    float ra = qperm_add<CTRL>(a);
    float rb = qperm_add<CTRL>(b);
    return (lane & off) ? rb : ra;
}
__device__ __forceinline__ float xred(float a, int off) {
    return a + __shfl_xor(a, off, 64);
}
__device__ __forceinline__ float xmerge(float a, float b, int off, int lane) {
    float ra = a + __shfl_xor(a, off, 64);
    float rb = b + __shfl_xor(b, off, 64);
    return (lane & off) ? rb : ra;
}

__device__ __forceinline__ float softplus_f(float x) {
    float e = __expf(-fabsf(x));
    return fmaxf(x, 0.0f) + __logf(1.0f + e);
}

__device__ __forceinline__ float rdlane(float x, int l) {
    return __int_as_float(__builtin_amdgcn_readlane(__float_as_int(x), l));
}

__global__ __launch_bounds__(256) void intensity_loss_kernel(
    const float* __restrict__ duration,   // [B]
    const float* __restrict__ cx,         // [B,H]
    const float* __restrict__ cbarx,      // [B,H]
    const float* __restrict__ deltx,      // [B,H]
    const float* __restrict__ ox,         // [B,H]
    const float* __restrict__ W,          // [H]
    const float* __restrict__ bptr,       // [1]
    const float* __restrict__ u,          // [NS,B]
    float* __restrict__ out,              // [B]
    int B)
{
    const int wave = threadIdx.x >> 6;
    const int lane = threadIdx.x & 63;
    const int row  = blockIdx.x * ROWS_PER_BLOCK + wave;
    if (row >= B) return;

    const size_t base = (size_t)row * HDIM + (size_t)(lane << 2);

    const float4 vcx = *reinterpret_cast<const float4*>(cx    + base);
    const float4 vcb = *reinterpret_cast<const float4*>(cbarx + base);
    const float4 vdl = *reinterpret_cast<const float4*>(deltx + base);
    const float4 vox = *reinterpret_cast<const float4*>(ox    + base);
    const float4 vw  = *reinterpret_cast<const float4*>(W + (lane << 2));

    const float dur = duration[row];

    // one u sample per lane: lane k (1..10) will evaluate MC sample k-1
    int sidx = lane - 1;
    sidx = sidx < 0 ? 0 : (sidx > NS - 1 ? NS - 1 : sidx);
    const float ul = u[(size_t)sidx * (size_t)B + (size_t)row];

    // per-row invariants (R15 structure)
    float cb[4]  = {vcb.x, vcb.y, vcb.z, vcb.w};
    float dx[4]  = {vcx.x - vcb.x, vcx.y - vcb.y, vcx.z - vcb.z, vcx.w - vcb.w};
    float dle[4] = {-vdl.x * dur, -vdl.y * dur, -vdl.z * dur, -vdl.w * dur};
    float ow[4]  = {vox.x * vw.x, vox.y * vw.y, vox.z * vw.z, vox.w * vw.w};
    float owa[4];
#pragma unroll
    for (int j = 0; j < 4; ++j) owa[j] = ow[j] * TA1;

    // c(u) = cb + dx*e^{dle*u} as cubic in u (deg-3 exp folded; R15-proven)
    float q0[4], q1[4], q2[4], q3[4];
#pragma unroll
    for (int j = 0; j < 4; ++j) {
        float t1 = dx[j] * dle[j];
        float t2 = t1 * dle[j];
        float t3 = t2 * dle[j];
        q0[j] = fmaf(dx[j], XC0, cb[j]);
        q1[j] = XC1 * t1;
        q2[j] = XC2 * t2;
        q3[j] = XC3 * t3;
    }

    // 4-element rational-sum -> single fraction N/P (R15-proven)
    auto np4 = [&](float c0, float c1, float c2, float c3, float& N, float& P) {
        float y0 = c0 * c0, y1 = c1 * c1, y2 = c2 * c2, y3 = c3 * c3;
        float d0 = fmaf(y0, fmaf(y0, TB2, TB1), 1.0f);
        float d1 = fmaf(y1, fmaf(y1, TB2, TB1), 1.0f);
        float d2 = fmaf(y2, fmaf(y2, TB2, TB1), 1.0f);
        float d3 = fmaf(y3, fmaf(y3, TB2, TB1), 1.0f);
        float n0 = c0 * fmaf(y0, owa[0], ow[0]);
        float n1 = c1 * fmaf(y1, owa[1], ow[1]);
        float n2 = c2 * fmaf(y2, owa[2], ow[2]);
        float n3 = c3 * fmaf(y3, owa[3], ow[3]);
        float p01 = d0 * d1, p23 = d2 * d3;
        float N01 = fmaf(n1, d0, n0 * d1);
        float N23 = fmaf(n3, d2, n2 * d3);
        N = fmaf(N23, p01, N01 * p23);
        P = p01 * p23;
    };
    auto eval_node = [&](float tt, float& N, float& P) {
        float cc[4];
#pragma unroll
        for (int j = 0; j < 4; ++j) {
            float c = fmaf(q3[j], tt, q2[j]);
            c = fmaf(c, tt, q1[j]);
            cc[j] = fmaf(c, tt, q0[j]);
        }
        np4(cc[0], cc[1], cc[2], cc[3], N, P);
    };

    // exact z_lane at the 5 nodes; node0 (u=0) uses c = cx directly (no exp)
    float z0, z1, z2, z3, z4;
    {
        float N, P;
        np4(vcx.x, vcx.y, vcx.z, vcx.w, N, P);
        z0 = N * __builtin_amdgcn_rcpf(P);
    }
    {
        float Na, Pa, Nb, Pb;
        eval_node(TN1, Na, Pa);
        eval_node(0.5f, Nb, Pb);
        float R = __builtin_amdgcn_rcpf(Pa * Pb);
        z1 = Na * (R * Pb);
        z2 = Nb * (R * Pa);
    }
    {
        float Na, Pa, Nb, Pb;
        eval_node(TN3, Na, Pa);
        eval_node(1.0f, Nb, Pb);
        float R = __builtin_amdgcn_rcpf(Pa * Pb);
        z3 = Na * (R * Pb);
        z4 = Nb * (R * Pa);   // exact z(1) -> nll node
    }

    // node values -> monomial coeffs (inverse Vandermonde, Lobatto nodes;
    // columns verified: partition of unity + Z(1)=z4 exact)
    float g0 = z0;
    float g1 = -11.0f * z0;
    g1 = fmaf(13.6568542f, z1, g1);
    g1 = fmaf(-4.0f, z2, g1);
    g1 = fmaf(2.34314575f, z3, g1);
    g1 -= z4;
    float g2 = 34.0f * z0;
    g2 = fmaf(-56.9705627f, z1, g2);
    g2 = fmaf(36.0f, z2, g2);
    g2 = fmaf(-23.0294373f, z3, g2);
    g2 = fmaf(10.0f, z4, g2);
    float g3 = -40.0f * z0;
    g3 = fmaf(75.3137085f, z1, g3);
    g3 = fmaf(-64.0f, z2, g3);
    g3 = fmaf(52.6862915f, z3, g3);
    g3 = fmaf(-24.0f, z4, g3);
    float g4 = 16.0f * z0;
    g4 = fmaf(-32.0f, z1, g4);
    g4 = fmaf(32.0f, z2, g4);
    g4 = fmaf(-32.0f, z3, g4);
    g4 = fmaf(16.0f, z4, g4);

    // wave-reduce the 5 coefficients (merge tree, 5 DS ops)
    float m01 = xmergeq<QP_XOR1>(g0, g1, 1, lane);
    float m23 = xmergeq<QP_XOR1>(g2, g3, 1, lane);
    float m4  = qperm_add<QP_XOR1>(g4);
    float qq0 = xmergeq<QP_XOR2>(m01, m23, 2, lane);
    float qq1 = qperm_add<QP_XOR2>(m4);
    float f   = xmerge(qq0, qq1, 4, lane);   // lane&7: 0..3 -> g_{lane&3}, >=4 -> g4
    f = xred(f, 8);
    f = xred(f, 16);
    f = xred(f, 32);

    // row-level quartic: lane 0 evaluates u=1 (exact nll), lanes 1..10 the MC samples
    const float G0 = rdlane(f, 0), G1 = rdlane(f, 1), G2 = rdlane(f, 2),
                G3 = rdlane(f, 3), G4 = rdlane(f, 4);
    const float ut = (lane == 0) ? 1.0f : ul;
    float Z = fmaf(G4, ut, G3);
    Z = fmaf(Z, ut, G2);
    Z = fmaf(Z, ut, G1);
    Z = fmaf(Z, ut, G0);

    const float bb = bptr[0];
    float sp   = softplus_f(Z + bb);
    float nllv = -__logf(sp + EPS_F);
    const float scale = dur * (1.0f / (float)NS);

    float contrib = (lane == 0) ? nllv
                  : ((lane <= NS) ? sp * scale : 0.0f);

    // lanes 0..10 -> lane 0 (within 16): xor8,4 DS; xor2,1 DPP
    contrib = xred(contrib, 8);
    contrib = xred(contrib, 4);
    contrib = qperm_add<QP_XOR2>(contrib);
    contrib = qperm_add<QP_XOR1>(contrib);

    if (lane == 0) out[row] = contrib;
}

extern "C" void kernel_launch(void* const* d_in, const int* in_sizes, int n_in,
                              void* d_out, int out_size, void* d_ws, size_t ws_size,
                              hipStream_t stream) {
    const float* duration = (const float*)d_in[0];
    const float* cx       = (const float*)d_in[1];
    const float* cbarx    = (const float*)d_in[2];
    const float* deltx    = (const float*)d_in[3];
    const float* ox       = (const float*)d_in[4];
    const float* W        = (const float*)d_in[5];
    const float* b        = (const float*)d_in[6];
    const float* u        = (const float*)d_in[7];
    float* out            = (float*)d_out;

    const int B = in_sizes[0];           // 65536
    const int grid = (B + ROWS_PER_BLOCK - 1) / ROWS_PER_BLOCK;

    intensity_loss_kernel<<<grid, 256, 0, stream>>>(
        duration, cx, cbarx, deltx, ox, W, b, u, out, B);
}